// Round 18
// baseline (74.798 us; speedup 1.0000x reference)
//
#include <hip/hip_runtime.h>
#include <hip/hip_bf16.h>

typedef float          f32x4  __attribute__((ext_vector_type(4)));
typedef short          bf16x8 __attribute__((ext_vector_type(8)));
typedef unsigned short u16x4  __attribute__((ext_vector_type(4)));

#define Bsz  8192
#define Dsz  64
#define Hsz  128
#define Tsz  41
#define ROWS 16
#define NT   256

#define MFMA(a,b,c) __builtin_amdgcn_mfma_f32_16x16x32_bf16((a),(b),(c),0,0,0)

__device__ __forceinline__ float fast_tanh(float x) {
    float ax = __builtin_fabsf(x);
    float e  = __expf(-2.0f * ax);
    float r  = (1.0f - e) * __builtin_amdgcn_rcpf(1.0f + e);
    return __builtin_copysignf(r, x);
}

__device__ __forceinline__ unsigned short bf2u(__hip_bfloat16 h) {
    union { __hip_bfloat16 b; unsigned short u; } v; v.b = h; return v.u;
}

union FragU { bf16x8 f; unsigned short h[8]; };

// pack 8 f32 -> one plain bf16 fragment (weights, init only)
__device__ __forceinline__ bf16x8 pack8(const float* x) {
    FragU H;
    #pragma unroll
    for (int i = 0; i < 8; ++i) H.h[i] = bf2u(__float2bfloat16(x[i]));
    return H.f;
}

// plain bf16 quad pack (z and a operand paths)
__device__ __forceinline__ u16x4 packq(const f32x4& x) {
    u16x4 H;
    #pragma unroll
    for (int i = 0; i < 4; ++i) H[i] = bf2u(__float2bfloat16(x[i]));
    return H;
}

__device__ __forceinline__ bf16x8 ldb128(const unsigned short* base, int byteoff) {
    return *(const bf16x8*)((const char*)base + byteoff);
}
__device__ __forceinline__ void stb64(unsigned short* base, int byteoff, u16x4 v) {
    *(u16x4*)((char*)base + byteoff) = v;
}

__global__ __launch_bounds__(NT, 2)
void ode_mfma18(const float* __restrict__ z0, const float* __restrict__ t,
                const float* __restrict__ W1, const float* __restrict__ b1,
                const float* __restrict__ W2, const float* __restrict__ b2,
                float* __restrict__ out)
{
    // a: double-buffered bf16 tile (ONE barrier per substep, WAR-safe).
    // z: per-wave bf16 scratch — wave-coherent C-layout -> B-frag redistribution,
    //    NO barrier (each wave computes the full dz redundantly; identical values).
    __shared__ __align__(16) unsigned short aHs[2][ROWS * Hsz];
    __shared__ __align__(16) unsigned short zscr[4 * ROWS * Dsz];
    __shared__ float ts[Tsz];

    const int tid  = threadIdx.x;
    const int lane = tid & 63;
    const int w    = tid >> 6;   // wave: layer1 h-cols 32w..+31; layer2 full d (redundant)
    const int g    = lane >> 4;
    const int c    = lane & 15;  // batch row within tile
    const int r0   = blockIdx.x * ROWS;

    if (tid < Tsz) ts[tid] = t[tid];

    // ---- full z master in registers: zf[mt][reg] = z[batch=c][d=16mt+4g+reg] ----
    f32x4 zf[4];
    #pragma unroll
    for (int mt = 0; mt < 4; ++mt)
        zf[mt] = *(const f32x4*)&z0[(r0 + c) * Dsz + 16*mt + 4*g];

    // ---- W1^T A-fragments: lane holds W1T[h=16(2w+nt)+c][d=32kt+8g+i] ----
    bf16x8 w1t[2][2];   // [nt][kt]
    #pragma unroll
    for (int nt = 0; nt < 2; ++nt) {
        const int n = 32*w + 16*nt + c;
        #pragma unroll
        for (int kt = 0; kt < 2; ++kt) {
            float tmp[8];
            #pragma unroll
            for (int i = 0; i < 8; ++i) tmp[i] = W1[(32*kt + 8*g + i) * Hsz + n];
            w1t[nt][kt] = pack8(tmp);
        }
    }
    // ---- W2^T A-fragments, FULL d per wave: W2T[d=16mt+c][h=32kt2+8g+i] ----
    bf16x8 w2t[4][4];   // [mt][kt2]
    #pragma unroll
    for (int mt = 0; mt < 4; ++mt) {
        const int n = 16*mt + c;
        #pragma unroll
        for (int kt2 = 0; kt2 < 4; ++kt2) {
            float tmp[8];
            #pragma unroll
            for (int i = 0; i < 8; ++i) tmp[i] = W2[(32*kt2 + 8*g + i) * Dsz + n];
            w2t[mt][kt2] = pack8(tmp);
        }
    }
    f32x4 b1v[2], b2v[4];
    #pragma unroll
    for (int nt = 0; nt < 2; ++nt)
        #pragma unroll
        for (int reg = 0; reg < 4; ++reg)
            b1v[nt][reg] = b1[16*(2*w + nt) + 4*g + reg];
    #pragma unroll
    for (int mt = 0; mt < 4; ++mt)
        #pragma unroll
        for (int reg = 0; reg < 4; ++reg)
            b2v[mt][reg] = b2[16*mt + 4*g + reg];

    // ---- loop-invariant swizzled LDS byte offsets ----
    const int zbase = w * (ROWS * Dsz * 2);     // per-wave scratch base (bytes)
    int zw[4], zrd[2], aw[2], ard[4];
    #pragma unroll
    for (int mt = 0; mt < 4; ++mt)
        zw[mt] = zbase + ((c*128 + (16*mt + 4*g)*2) ^ ((c & 7) << 4));     // b64 write
    #pragma unroll
    for (int kt = 0; kt < 2; ++kt)
        zrd[kt] = zbase + ((c*128 + (32*kt + 8*g)*2) ^ ((c & 7) << 4));    // b128 read
    #pragma unroll
    for (int nt = 0; nt < 2; ++nt)
        aw[nt] = (c*256 + (32*w + 16*nt + 4*g)*2) ^ ((c & 7) << 4);        // b64 write
    #pragma unroll
    for (int kt2 = 0; kt2 < 4; ++kt2)
        ard[kt2] = (c*256 + (32*kt2 + 8*g)*2) ^ ((c & 7) << 4);            // b128 read

    // initial z -> own scratch (wave-local; barrier below is only for ts)
    #pragma unroll
    for (int mt = 0; mt < 4; ++mt) stb64(zscr, zw[mt], packq(zf[mt]));
    __syncthreads();

    const int n_steps = (int)ceilf(fabsf(ts[1] - ts[0]) / 0.05f);   // = 2 (exact in f32)

    int cur = 0;
    for (int iv = 0; iv < Tsz - 1; ++iv) {
        const float h = (ts[iv + 1] - ts[iv]) / (float)n_steps;
        for (int s = 0; s < n_steps; ++s) {
            // ---- layer 1: a^T = tanh(W1T @ bf16(z^T) + b1); write a -> buf cur ----
            bf16x8 zb0 = ldb128(zscr, zrd[0]), zb1 = ldb128(zscr, zrd[1]);
            unsigned short* aH = aHs[cur];
            #pragma unroll
            for (int nt = 0; nt < 2; ++nt) {
                f32x4 aA = b1v[nt];
                aA = MFMA(w1t[nt][0], zb0, aA);
                aA = MFMA(w1t[nt][1], zb1, aA);
                f32x4 tv;
                #pragma unroll
                for (int reg = 0; reg < 4; ++reg) tv[reg] = fast_tanh(aA[reg]);
                stb64(aH, aw[nt], packq(tv));
            }
            __syncthreads();             // the ONLY barrier per substep
            // ---- layer 2 (redundant full-d per wave): dz^T = W2T @ bf16(a^T) + b2 ----
            bf16x8 ah0 = ldb128(aH, ard[0]), ah1 = ldb128(aH, ard[1]);
            bf16x8 ah2 = ldb128(aH, ard[2]), ah3 = ldb128(aH, ard[3]);
            #pragma unroll
            for (int mt = 0; mt < 4; ++mt) {
                f32x4 dA = b2v[mt];
                dA = MFMA(w2t[mt][0], ah0, dA);
                dA = MFMA(w2t[mt][1], ah1, dA);
                dA = MFMA(w2t[mt][2], ah2, dA);
                dA = MFMA(w2t[mt][3], ah3, dA);
                zf[mt] += h * dA;
                stb64(zscr, zw[mt], packq(zf[mt]));   // wave-local scratch, no barrier
            }
            cur ^= 1;
        }
    }

    // ---- write result ----
    #pragma unroll
    for (int mt = 0; mt < 4; ++mt)
        *(f32x4*)&out[(r0 + c) * Dsz + 16*mt + 4*g] = zf[mt];
}

extern "C" void kernel_launch(void* const* d_in, const int* in_sizes, int n_in,
                              void* d_out, int out_size, void* d_ws, size_t ws_size,
                              hipStream_t stream) {
    const float* z0 = (const float*)d_in[0];
    const float* t  = (const float*)d_in[1];
    const float* W1 = (const float*)d_in[2];
    const float* b1 = (const float*)d_in[3];
    const float* W2 = (const float*)d_in[4];
    const float* b2 = (const float*)d_in[5];
    float* out = (float*)d_out;
    (void)in_sizes; (void)n_in; (void)out_size; (void)d_ws; (void)ws_size;

    ode_mfma18<<<dim3(Bsz / ROWS), dim3(NT), 0, stream>>>(z0, t, W1, b1, W2, b2, out);
}

// Round 19
// 57.655 us; speedup vs baseline: 1.2974x; 1.2974x over previous
//
#include <hip/hip_runtime.h>
#include <hip/hip_bf16.h>

typedef float          f32x4  __attribute__((ext_vector_type(4)));
typedef short          bf16x8 __attribute__((ext_vector_type(8)));
typedef unsigned short u16x4  __attribute__((ext_vector_type(4)));

#define Bsz  8192
#define Dsz  64
#define Hsz  128
#define Tsz  41
#define ROWS 16
#define NT   256

#define MFMA(a,b,c) __builtin_amdgcn_mfma_f32_16x16x32_bf16((a),(b),(c),0,0,0)

__device__ __forceinline__ float fast_tanh(float x) {
    float ax = __builtin_fabsf(x);
    float e  = __expf(-2.0f * ax);
    float r  = (1.0f - e) * __builtin_amdgcn_rcpf(1.0f + e);
    return __builtin_copysignf(r, x);
}

__device__ __forceinline__ unsigned short bf2u(__hip_bfloat16 h) {
    union { __hip_bfloat16 b; unsigned short u; } v; v.b = h; return v.u;
}

union FragU { bf16x8 f; unsigned short h[8]; };

// pack 8 f32 -> one plain bf16 fragment (weights, init only — residuals dropped:
// R12/R15/R16/R17 showed output absmax insensitive to precision down to bf16)
__device__ __forceinline__ bf16x8 pack8(const float* x) {
    FragU H;
    #pragma unroll
    for (int i = 0; i < 8; ++i) H.h[i] = bf2u(__float2bfloat16(x[i]));
    return H.f;
}

// plain bf16 quad pack (z and a operand paths)
__device__ __forceinline__ u16x4 packq(const f32x4& x) {
    u16x4 H;
    #pragma unroll
    for (int i = 0; i < 4; ++i) H[i] = bf2u(__float2bfloat16(x[i]));
    return H;
}

__device__ __forceinline__ bf16x8 ldb128(const unsigned short* base, int byteoff) {
    return *(const bf16x8*)((const char*)base + byteoff);
}
__device__ __forceinline__ void stb64(unsigned short* base, int byteoff, u16x4 v) {
    *(u16x4*)((char*)base + byteoff) = v;
}

__global__ __launch_bounds__(NT, 2)
void ode_mfma17(const float* __restrict__ z0, const float* __restrict__ t,
                const float* __restrict__ W1, const float* __restrict__ b1,
                const float* __restrict__ W2, const float* __restrict__ b2,
                float* __restrict__ out)
{
    // z and a: single plain-bf16 tiles; weights: plain bf16 fragments.
    // [batch_row][feature], byte-index XOR-swizzled by (row&7)<<4.
    __shared__ __align__(16) unsigned short zHs[ROWS * Dsz];
    __shared__ __align__(16) unsigned short aHs[ROWS * Hsz];
    __shared__ float ts[Tsz];

    const int tid  = threadIdx.x;
    const int lane = tid & 63;
    const int w    = tid >> 6;   // wave: layer1 h-cols 32w..+31, layer2 d-cols 16w..+15
    const int g    = lane >> 4;
    const int c    = lane & 15;  // batch row within tile
    const int r0   = blockIdx.x * ROWS;

    if (tid < Tsz) ts[tid] = t[tid];

    // ---- z master in registers: zreg[reg] = z[batch=c][d = 16w + 4g + reg] ----
    f32x4 zreg = *(const f32x4*)&z0[(r0 + c) * Dsz + 16*w + 4*g];

    // ---- W1^T A-fragments: lane holds W1T[h=16(2w+nt)+c][d=32kt+8g+i] ----
    bf16x8 w1t[2][2];   // [nt][kt]
    #pragma unroll
    for (int nt = 0; nt < 2; ++nt) {
        const int n = 32*w + 16*nt + c;
        #pragma unroll
        for (int kt = 0; kt < 2; ++kt) {
            float tmp[8];
            #pragma unroll
            for (int i = 0; i < 8; ++i) tmp[i] = W1[(32*kt + 8*g + i) * Hsz + n];
            w1t[nt][kt] = pack8(tmp);
        }
    }
    // ---- W2^T A-fragments: lane holds W2T[d=16w+c][h=32kt2+8g+i] ----
    bf16x8 w2t[4];      // [kt2]
    {
        const int n = 16*w + c;
        #pragma unroll
        for (int kt2 = 0; kt2 < 4; ++kt2) {
            float tmp[8];
            #pragma unroll
            for (int i = 0; i < 8; ++i) tmp[i] = W2[(32*kt2 + 8*g + i) * Dsz + n];
            w2t[kt2] = pack8(tmp);
        }
    }
    f32x4 b1v[2], b2v;
    #pragma unroll
    for (int nt = 0; nt < 2; ++nt)
        #pragma unroll
        for (int reg = 0; reg < 4; ++reg)
            b1v[nt][reg] = b1[16*(2*w + nt) + 4*g + reg];
    #pragma unroll
    for (int reg = 0; reg < 4; ++reg) b2v[reg] = b2[16*w + 4*g + reg];

    // ---- loop-invariant swizzled LDS byte offsets ----
    const int zw = (c*128 + (16*w + 4*g)*2) ^ ((c & 7) << 4);          // b64 write
    int zrd[2], aw[2], ard[4];
    #pragma unroll
    for (int kt = 0; kt < 2; ++kt)
        zrd[kt] = (c*128 + (32*kt + 8*g)*2) ^ ((c & 7) << 4);          // b128 read
    #pragma unroll
    for (int nt = 0; nt < 2; ++nt)
        aw[nt] = (c*256 + (32*w + 16*nt + 4*g)*2) ^ ((c & 7) << 4);    // b64 write
    #pragma unroll
    for (int kt2 = 0; kt2 < 4; ++kt2)
        ard[kt2] = (c*256 + (32*kt2 + 8*g)*2) ^ ((c & 7) << 4);        // b128 read

    auto z_to_lds = [&]() {
        stb64(zHs, zw, packq(zreg));     // one b64
    };

    z_to_lds();
    __syncthreads();

    const int n_steps = (int)ceilf(fabsf(ts[1] - ts[0]) / 0.05f);   // = 2 (exact in f32)

    for (int iv = 0; iv < Tsz - 1; ++iv) {
        const float h = (ts[iv + 1] - ts[iv]) / (float)n_steps;
        for (int s = 0; s < n_steps; ++s) {
            // ---- layer 1 (transposed): a^T = tanh(W1T @ bf16(z^T) + b1) ----
            bf16x8 zh0 = ldb128(zHs, zrd[0]), zh1 = ldb128(zHs, zrd[1]);
            #pragma unroll
            for (int nt = 0; nt < 2; ++nt) {
                f32x4 aA = b1v[nt];
                aA = MFMA(w1t[nt][0], zh0, aA);
                aA = MFMA(w1t[nt][1], zh1, aA);
                f32x4 tv;
                #pragma unroll
                for (int reg = 0; reg < 4; ++reg) tv[reg] = fast_tanh(aA[reg]);
                stb64(aHs, aw[nt], packq(tv));   // one b64 store
            }
            __syncthreads();
            // ---- layer 2 (transposed): dz^T = W2T @ bf16(a^T) + b2 ----
            bf16x8 ah0 = ldb128(aHs, ard[0]), ah1 = ldb128(aHs, ard[1]);
            bf16x8 ah2 = ldb128(aHs, ard[2]), ah3 = ldb128(aHs, ard[3]);
            f32x4 dA = b2v;
            f32x4 dB = {0,0,0,0};
            dA = MFMA(w2t[0], ah0, dA);
            dB = MFMA(w2t[1], ah1, dB);
            dA = MFMA(w2t[2], ah2, dA);
            dB = MFMA(w2t[3], ah3, dB);
            f32x4 dz = dA + dB;
            zreg += h * dz;
            z_to_lds();                  // 1 b64 write
            __syncthreads();
        }
    }

    // ---- write result (one dwordx4 per lane) ----
    *(f32x4*)&out[(r0 + c) * Dsz + 16*w + 4*g] = zreg;
}

extern "C" void kernel_launch(void* const* d_in, const int* in_sizes, int n_in,
                              void* d_out, int out_size, void* d_ws, size_t ws_size,
                              hipStream_t stream) {
    const float* z0 = (const float*)d_in[0];
    const float* t  = (const float*)d_in[1];
    const float* W1 = (const float*)d_in[2];
    const float* b1 = (const float*)d_in[3];
    const float* W2 = (const float*)d_in[4];
    const float* b2 = (const float*)d_in[5];
    float* out = (float*)d_out;
    (void)in_sizes; (void)n_in; (void)out_size; (void)d_ws; (void)ws_size;

    ode_mfma17<<<dim3(Bsz / ROWS), dim3(NT), 0, stream>>>(z0, t, W1, b1, W2, b2, out);
}